// Round 15
// baseline (2051.547 us; speedup 1.0000x reference)
//
#include <hip/hip_runtime.h>
#include <math.h>

// M3GNet-like GNN forward. N=10000 nodes, E=160000 edges, T=1200000 triplets,
// D=256, DM=64, H=1024, L=3, output = scalar mean energy (fp32).
//
// R14: k_edge_attn still VALU-bound (90% busy). Two cuts:
//  - silu via v_rcp_f32 (__builtin_amdgcn_rcpf) instead of exact fp32 div
//    (div lowered to ~10-slot div_scale/div_fmas/div_fixup sequence x4).
//  - edges processed in length-sorted order (bucket sort by segment length,
//    built once in setup): the 4 edges sharing a wave have near-equal
//    triplet counts -> no divergence waste (was ~1.5x).

#define DM 64
#define DMODEL 256
#define HDIM 1024
#define LBINS 512

typedef unsigned short bf16_t;
typedef __attribute__((ext_vector_type(8))) short s8v;    // 8 bf16 (4 VGPRs)
typedef __attribute__((ext_vector_type(4))) float f4;     // MFMA acc

__device__ __forceinline__ bf16_t f2bf(float f) {
    unsigned int u = __float_as_uint(f);
    return (bf16_t)((u + 0x7FFFu + ((u >> 16) & 1u)) >> 16);   // RNE
}
__device__ __forceinline__ float bf_lo(unsigned int u) {
    return __uint_as_float(u << 16);
}
__device__ __forceinline__ float bf_hi(unsigned int u) {
    return __uint_as_float(u & 0xFFFF0000u);
}
__device__ __forceinline__ float silu_f(float u) {
    return u * __builtin_amdgcn_rcpf(1.f + __expf(-u));
}

__global__ void k_embed(const int* __restrict__ an, const float* __restrict__ emb,
                        bf16_t* __restrict__ x) {
    int n = blockIdx.x;
    int d = threadIdx.x;
    x[n * DMODEL + d] = f2bf(emb[an[n] * DMODEL + d]);
}

__global__ void k_edge_geom(const float* __restrict__ r, float* __restrict__ bl,
                            float* __restrict__ rn, int E) {
    int e = blockIdx.x * blockDim.x + threadIdx.x;
    if (e >= E) return;
    float a = r[e * 3 + 0], b = r[e * 3 + 1], c = r[e * 3 + 2];
    float l = sqrtf(a * a + b * b + c * c);
    bl[e] = l;
    float inv = 1.0f / l;
    rn[e * 3 + 0] = a * inv;
    rn[e * 3 + 1] = b * inv;
    rn[e * 3 + 2] = c * inv;
}

__global__ void k_hist(const int* __restrict__ idx, int* __restrict__ cnt, int M) {
    int t = blockIdx.x * blockDim.x + threadIdx.x;
    if (t < M) atomicAdd(&cnt[idx[t]], 1);
}

// ---- 3-phase exclusive scan ----
__global__ __launch_bounds__(256) void k_scan_part(
    const int* __restrict__ cnt, int* __restrict__ bsum, int M) {
    __shared__ int sm[4];
    int tid = threadIdx.x;
    int i = blockIdx.x * 256 + tid;
    int v = (i < M) ? cnt[i] : 0;
    for (int off = 32; off > 0; off >>= 1) v += __shfl_xor(v, off, 64);
    if ((tid & 63) == 0) sm[tid >> 6] = v;
    __syncthreads();
    if (tid == 0) bsum[blockIdx.x] = sm[0] + sm[1] + sm[2] + sm[3];
}

__global__ __launch_bounds__(1024) void k_scan_mid(int* __restrict__ bsum, int nb) {
    __shared__ int sm[1024];
    int tid = threadIdx.x;
    int v = (tid < nb) ? bsum[tid] : 0;
    sm[tid] = v;
    __syncthreads();
    for (int off = 1; off < 1024; off <<= 1) {
        int u = (tid >= off) ? sm[tid - off] : 0;
        __syncthreads();
        sm[tid] += u;
        __syncthreads();
    }
    if (tid < nb) bsum[tid] = sm[tid] - v;
}

__global__ __launch_bounds__(256) void k_scan_final(
    const int* __restrict__ cnt, const int* __restrict__ bsum,
    int* __restrict__ rowp, int M, int total) {
    __shared__ int sm[256];
    int tid = threadIdx.x;
    int i = blockIdx.x * 256 + tid;
    int v = (i < M) ? cnt[i] : 0;
    sm[tid] = v;
    __syncthreads();
    for (int off = 1; off < 256; off <<= 1) {
        int u = (tid >= off) ? sm[tid - off] : 0;
        __syncthreads();
        sm[tid] += u;
        __syncthreads();
    }
    if (i < M) rowp[i] = bsum[blockIdx.x] + sm[tid] - v;
    if (i == 0) rowp[M] = total;
}

// scatter triplets into segment order; packed = (src, theta-bits).
__global__ void k_scatter(const int* __restrict__ ts, const int* __restrict__ td,
                          const int* __restrict__ rowp, int* __restrict__ cursor,
                          const float* __restrict__ rn,
                          int2* __restrict__ packed, int T) {
    int t = blockIdx.x * blockDim.x + threadIdx.x;
    if (t >= T) return;
    int a = ts[t], b = td[t];
    float d = rn[a * 3 + 0] * rn[b * 3 + 0]
            + rn[a * 3 + 1] * rn[b * 3 + 1]
            + rn[a * 3 + 2] * rn[b * 3 + 2];
    d = fminf(1.0f, fmaxf(-1.0f, d));
    float th = acosf(d);
    int pos = rowp[b] + atomicAdd(&cursor[b], 1);
    packed[pos] = make_int2(a, __float_as_int(th));
}

__global__ void k_escatter(const int* __restrict__ gd, const int* __restrict__ erowp,
                           int* __restrict__ cursor, int* __restrict__ eord, int E) {
    int e = blockIdx.x * blockDim.x + threadIdx.x;
    if (e >= E) return;
    int n = gd[e];
    int pos = erowp[n] + atomicAdd(&cursor[n], 1);
    eord[pos] = e;
}

// histogram of segment lengths (capped at LBINS-1)
__global__ void k_lenhist(const int* __restrict__ rowp, int* __restrict__ lbin,
                          int E) {
    int e = blockIdx.x * blockDim.x + threadIdx.x;
    if (e >= E) return;
    int len = min(rowp[e + 1] - rowp[e], LBINS - 1);
    atomicAdd(&lbin[len], 1);
}

// scatter edge ids into length-sorted order
__global__ void k_lenscatter(const int* __restrict__ rowp, const int* __restrict__ lbin,
                             int* __restrict__ lcur, int* __restrict__ aord, int E) {
    int e = blockIdx.x * blockDim.x + threadIdx.x;
    if (e >= E) return;
    int len = min(rowp[e + 1] - rowp[e], LBINS - 1);
    int pos = lbin[len] + atomicAdd(&lcur[len], 1);
    aord[pos] = e;
}

// 32x32 tiled transpose + cast: src fp32 [K][Nn] -> dst bf16 [Nn][K].
__global__ __launch_bounds__(256) void k_castT(
    const float* __restrict__ src, bf16_t* __restrict__ dst, int K, int Nn) {
    __shared__ float tile[32][33];
    int k0 = blockIdx.x * 32, n0 = blockIdx.y * 32;
    int tx = threadIdx.x & 31, ty = threadIdx.x >> 5;
    #pragma unroll
    for (int i = 0; i < 4; ++i) {
        int row = ty + i * 8;
        tile[row][tx] = src[(size_t)(k0 + row) * Nn + n0 + tx];
    }
    __syncthreads();
    #pragma unroll
    for (int i = 0; i < 4; ++i) {
        int row = ty + i * 8;
        dst[(size_t)(n0 + row) * K + k0 + tx] = f2bf(tile[tx][row]);
    }
}

// MFMA node_proj: xs = x@Wsrc + bs, xd = x@Wdst + bd (fp32 out).
__global__ __launch_bounds__(256) void k_node_proj(
    const bf16_t* __restrict__ xb,
    const bf16_t* __restrict__ Wst, const float* __restrict__ bs,
    const bf16_t* __restrict__ Wdt, const float* __restrict__ bd,
    float* __restrict__ xs, float* __restrict__ xd, int N) {
    int tid = threadIdx.x;
    int w = tid >> 6, lane = tid & 63;
    int col = lane & 15, quad = lane >> 4;
    int m0 = blockIdx.x * 64 + w * 16;
    f4 as[4] = {{0.f,0.f,0.f,0.f},{0.f,0.f,0.f,0.f},
                {0.f,0.f,0.f,0.f},{0.f,0.f,0.f,0.f}};
    f4 ad[4] = {{0.f,0.f,0.f,0.f},{0.f,0.f,0.f,0.f},
                {0.f,0.f,0.f,0.f},{0.f,0.f,0.f,0.f}};
    #pragma unroll
    for (int k0 = 0; k0 < DMODEL; k0 += 32) {
        s8v a = *(const s8v*)&xb[(size_t)(m0 + col) * DMODEL + k0 + quad * 8];
        #pragma unroll
        for (int t = 0; t < 4; ++t) {
            s8v b1v = *(const s8v*)&Wst[(size_t)(t * 16 + col) * DMODEL + k0 + quad * 8];
            as[t] = __builtin_amdgcn_mfma_f32_16x16x32_bf16(a, b1v, as[t], 0, 0, 0);
            s8v b2v = *(const s8v*)&Wdt[(size_t)(t * 16 + col) * DMODEL + k0 + quad * 8];
            ad[t] = __builtin_amdgcn_mfma_f32_16x16x32_bf16(a, b2v, ad[t], 0, 0, 0);
        }
    }
    #pragma unroll
    for (int t = 0; t < 4; ++t) {
        int c = t * 16 + col;
        float bsv = bs[c], bdv = bd[c];
        #pragma unroll
        for (int r = 0; r < 4; ++r) {
            int m = m0 + quad * 4 + r;
            if (m < N) {
                xs[(size_t)m * DM + c] = as[t][r] + bsv;
                xd[(size_t)m * DM + c] = ad[t][r] + bdv;
            }
        }
    }
}

// MFMA k_xij: xij[e][c] = (RBF(bl[e]) @ Wedge)[c] + xs[gs[e]][c] + xd[gd[e]][c] + be[c]
__global__ __launch_bounds__(256) void k_xij(
    const float* __restrict__ bl, const bf16_t* __restrict__ Wedgt,
    const float* __restrict__ be,
    const float* __restrict__ xs, const float* __restrict__ xd,
    const int* __restrict__ gs, const int* __restrict__ gd,
    bf16_t* __restrict__ xij, int E) {
    int tid = threadIdx.x;
    int w = tid >> 6, lane = tid & 63;
    int col = lane & 15, quad = lane >> 4;
    int m0 = blockIdx.x * 64 + w * 16;
    const float step = 8.0f / 255.0f;
    const float gamma = (255.0f / 8.0f) * (255.0f / 8.0f);
    int me = m0 + col;
    float blv = (me < E) ? bl[me] : 0.f;
    f4 acc[4] = {{0.f,0.f,0.f,0.f},{0.f,0.f,0.f,0.f},
                 {0.f,0.f,0.f,0.f},{0.f,0.f,0.f,0.f}};
    #pragma unroll
    for (int k0 = 0; k0 < DMODEL; k0 += 32) {
        s8v a;
        #pragma unroll
        for (int j = 0; j < 8; ++j) {
            float c = (float)(k0 + quad * 8 + j) * step;
            float dd = blv - c;
            a[j] = (short)f2bf(__expf(-gamma * dd * dd));
        }
        #pragma unroll
        for (int t = 0; t < 4; ++t) {
            s8v b = *(const s8v*)&Wedgt[(size_t)(t * 16 + col) * DMODEL + k0 + quad * 8];
            acc[t] = __builtin_amdgcn_mfma_f32_16x16x32_bf16(a, b, acc[t], 0, 0, 0);
        }
    }
    #pragma unroll
    for (int r = 0; r < 4; ++r) {
        int e = m0 + quad * 4 + r;
        if (e >= E) continue;
        int s = gs[e], d2 = gd[e];
        #pragma unroll
        for (int t = 0; t < 4; ++t) {
            int c = t * 16 + col;
            float v = acc[t][r] + xs[(size_t)s * DM + c] + xd[(size_t)d2 * DM + c] + be[c];
            xij[(size_t)e * DM + c] = f2bf(v);
        }
    }
}

// Fused logit+softmax+attend: 16-lane group per edge (length-sorted order),
// lane q = channels [4q, 4q+4). T_k = __cosf(k*theta); silu via v_rcp.
__global__ __launch_bounds__(256) void k_edge_attn(
    const bf16_t* __restrict__ xij, const int2* __restrict__ packed,
    const int* __restrict__ rowp, const int* __restrict__ aord,
    const float* __restrict__ attn_l, bf16_t* __restrict__ msg, int E) {
    int gtid = blockIdx.x * 256 + threadIdx.x;
    int ei = gtid >> 4;
    if (ei >= E) return;
    int e = aord[ei];
    int q = gtid & 15;
    int beg = rowp[e], end = rowp[e + 1];
    float a0 = 0.f, a1 = 0.f, a2 = 0.f, a3 = 0.f;
    if (beg < end) {
        uint2 ue = *(const uint2*)&xij[(size_t)e * DM + q * 4];
        float xe0 = bf_lo(ue.x), xe1 = bf_hi(ue.x);
        float xe2 = bf_lo(ue.y), xe3 = bf_hi(ue.y);
        float4 at = *(const float4*)&attn_l[q * 4];
        float kf = (float)(4 * q);
        float den = 0.f;
        for (int p = beg; p < end; ++p) {
            int2 pk = packed[p];
            int s = pk.x;
            float th = __int_as_float(pk.y);
            uint2 us = *(const uint2*)&xij[(size_t)s * DM + q * 4];
            float xs0 = bf_lo(us.x), xs1 = bf_hi(us.x);
            float xs2 = bf_lo(us.y), xs3 = bf_hi(us.y);
            float u0 = __cosf(kf * th) + xs0 + xe0;
            float u1 = __cosf((kf + 1.f) * th) + xs1 + xe1;
            float u2 = __cosf((kf + 2.f) * th) + xs2 + xe2;
            float u3 = __cosf((kf + 3.f) * th) + xs3 + xe3;
            float s0 = silu_f(u0), s1 = silu_f(u1);
            float s2 = silu_f(u2), s3 = silu_f(u3);
            float partial = fmaf(s0, at.x, fmaf(s1, at.y,
                            fmaf(s2, at.z, s3 * at.w)));
            #pragma unroll
            for (int off = 1; off < 16; off <<= 1)
                partial += __shfl_xor(partial, off, 64);
            float wg = __expf(partial);
            den += wg;
            a0 = fmaf(wg, xs0, a0);
            a1 = fmaf(wg, xs1, a1);
            a2 = fmaf(wg, xs2, a2);
            a3 = fmaf(wg, xs3, a3);
        }
        float inv = 1.f / den;
        a0 *= inv; a1 *= inv; a2 *= inv; a3 *= inv;
    }
    ushort4 o = {f2bf(a0), f2bf(a1), f2bf(a2), f2bf(a3)};
    *(ushort4*)&msg[(size_t)e * DM + q * 4] = o;
}

// thread per (node, channel-quad): sum bf16 msg -> bf16 ft.
__global__ __launch_bounds__(256) void k_aggregate(
    const bf16_t* __restrict__ msg, const int* __restrict__ erowp,
    const int* __restrict__ eord, bf16_t* __restrict__ ft, int N) {
    int gtid = blockIdx.x * 256 + threadIdx.x;
    int n = gtid >> 4;
    if (n >= N) return;
    int quad = gtid & 15;
    int beg = erowp[n], end = erowp[n + 1];
    float a0 = 0.f, a1 = 0.f, a2 = 0.f, a3 = 0.f;
    for (int j = beg; j < end; ++j) {
        uint2 uv = *(const uint2*)&msg[(size_t)eord[j] * DM + quad * 4];
        a0 += bf_lo(uv.x); a1 += bf_hi(uv.x);
        a2 += bf_lo(uv.y); a3 += bf_hi(uv.y);
    }
    ushort4 o = {f2bf(a0), f2bf(a1), f2bf(a2), f2bf(a3)};
    *(ushort4*)&ft[(size_t)n * DM + quad * 4] = o;
}

// MFMA ffn1: h = silu(ft(bf16) @ W1 + b1), h bf16. grid (157, 16).
__global__ __launch_bounds__(256) void k_ffn1(
    const bf16_t* __restrict__ ft, const bf16_t* __restrict__ W1t,
    const float* __restrict__ b1, bf16_t* __restrict__ h, int N) {
    int tid = threadIdx.x;
    int w = tid >> 6, lane = tid & 63;
    int col = lane & 15, quad = lane >> 4;
    int m0 = blockIdx.x * 64 + w * 16;
    int c0 = blockIdx.y * 64;
    f4 acc[4] = {{0.f,0.f,0.f,0.f},{0.f,0.f,0.f,0.f},
                 {0.f,0.f,0.f,0.f},{0.f,0.f,0.f,0.f}};
    #pragma unroll
    for (int k0 = 0; k0 < DM; k0 += 32) {
        s8v a = *(const s8v*)&ft[(size_t)(m0 + col) * DM + k0 + quad * 8];
        #pragma unroll
        for (int t = 0; t < 4; ++t) {
            s8v b = *(const s8v*)&W1t[(size_t)(c0 + t * 16 + col) * DM + k0 + quad * 8];
            acc[t] = __builtin_amdgcn_mfma_f32_16x16x32_bf16(a, b, acc[t], 0, 0, 0);
        }
    }
    #pragma unroll
    for (int t = 0; t < 4; ++t) {
        int c = c0 + t * 16 + col;
        float bb = b1[c];
        #pragma unroll
        for (int r = 0; r < 4; ++r) {
            int m = m0 + quad * 4 + r;
            if (m < N) {
                float v = acc[t][r] + bb;
                h[(size_t)m * HDIM + c] = f2bf(silu_f(v));
            }
        }
    }
}

// MFMA ffn2: x = h(bf16) @ W2 + b2 (bf16 out). grid (157, 4).
__global__ __launch_bounds__(256) void k_ffn2(
    const bf16_t* __restrict__ h, const bf16_t* __restrict__ W2t,
    const float* __restrict__ b2, bf16_t* __restrict__ x, int N) {
    int tid = threadIdx.x;
    int w = tid >> 6, lane = tid & 63;
    int col = lane & 15, quad = lane >> 4;
    int m0 = blockIdx.x * 64 + w * 16;
    int c0 = blockIdx.y * 64;
    f4 acc[4] = {{0.f,0.f,0.f,0.f},{0.f,0.f,0.f,0.f},
                 {0.f,0.f,0.f,0.f},{0.f,0.f,0.f,0.f}};
    for (int k0 = 0; k0 < HDIM; k0 += 32) {
        s8v a = *(const s8v*)&h[(size_t)(m0 + col) * HDIM + k0 + quad * 8];
        #pragma unroll
        for (int t = 0; t < 4; ++t) {
            s8v b = *(const s8v*)&W2t[(size_t)(c0 + t * 16 + col) * HDIM + k0 + quad * 8];
            acc[t] = __builtin_amdgcn_mfma_f32_16x16x32_bf16(a, b, acc[t], 0, 0, 0);
        }
    }
    #pragma unroll
    for (int t = 0; t < 4; ++t) {
        int c = c0 + t * 16 + col;
        float bb = b2[c];
        #pragma unroll
        for (int r = 0; r < 4; ++r) {
            int m = m0 + quad * 4 + r;
            if (m < N) x[(size_t)m * DMODEL + c] = f2bf(acc[t][r] + bb);
        }
    }
}

// grid-stride dot over bf16 x, one atomic per block.
__global__ __launch_bounds__(256) void k_out_reduce(
    const bf16_t* __restrict__ x, const float* __restrict__ Wfc,
    float* __restrict__ acc, int NT) {
    __shared__ float sm[4];
    int tid = threadIdx.x;
    float v = 0.f;
    int np = NT / 2;
    const unsigned int* xp = (const unsigned int*)x;
    for (int i = blockIdx.x * blockDim.x + tid; i < np; i += gridDim.x * blockDim.x) {
        unsigned int u = xp[i];
        int c = (2 * i) & (DMODEL - 1);
        v = fmaf(bf_lo(u), Wfc[c], v);
        v = fmaf(bf_hi(u), Wfc[c + 1], v);
    }
    for (int off = 32; off > 0; off >>= 1) v += __shfl_xor(v, off, 64);
    if ((tid & 63) == 0) sm[tid >> 6] = v;
    __syncthreads();
    if (tid == 0) {
        float s = sm[0] + sm[1] + sm[2] + sm[3];
        atomicAdd(acc, s);
    }
}

__global__ void k_out_final(const float* __restrict__ acc, const float* __restrict__ bfc,
                            float* __restrict__ out, float invN) {
    out[0] = acc[0] * invN + bfc[0];
}

extern "C" void kernel_launch(void* const* d_in, const int* in_sizes, int n_in,
                              void* d_out, int out_size, void* d_ws, size_t ws_size,
                              hipStream_t stream) {
    const int*   an    = (const int*)d_in[0];
    const int*   gs    = (const int*)d_in[1];
    const int*   gd    = (const int*)d_in[2];
    const int*   ts    = (const int*)d_in[3];
    const int*   td    = (const int*)d_in[4];
    const float* r     = (const float*)d_in[5];
    const float* emb   = (const float*)d_in[6];
    const float* Wsrc  = (const float*)d_in[7];
    const float* bsrc  = (const float*)d_in[8];
    const float* Wdst  = (const float*)d_in[9];
    const float* bdst  = (const float*)d_in[10];
    const float* Wedge = (const float*)d_in[11];
    const float* bedge = (const float*)d_in[12];
    const float* attn  = (const float*)d_in[13];
    const float* W1    = (const float*)d_in[14];
    const float* b1    = (const float*)d_in[15];
    const float* W2    = (const float*)d_in[16];
    const float* b2    = (const float*)d_in[17];
    const float* Wfc   = (const float*)d_in[18];
    const float* bfc   = (const float*)d_in[19];

    const int N = in_sizes[0];
    const int E = in_sizes[1];
    const int T = in_sizes[3];

    char* w = (char*)d_ws;
    size_t off = 0;
    auto alloc = [&](size_t bytes) {
        void* p = w + off;
        off += (bytes + 255) & ~(size_t)255;
        return p;
    };
    bf16_t* xb     = (bf16_t*)alloc((size_t)(N + 64) * DMODEL * 2);
    float*  rn     = (float*) alloc((size_t)E * 3 * 4);
    float*  bl     = (float*) alloc(((size_t)E + 64) * 4);
    int*    cnt    = (int*)   alloc((size_t)E * 4);
    int*    rowp   = (int*)   alloc(((size_t)E + 1) * 4);
    int*    bsum   = (int*)   alloc(4096);
    int2*   packed = (int2*)  alloc((size_t)T * 8);
    int*    ecnt   = (int*)   alloc((size_t)N * 4);
    int*    erowp  = (int*)   alloc(((size_t)N + 1) * 4);
    int*    eord   = (int*)   alloc((size_t)E * 4);
    int*    aord   = (int*)   alloc((size_t)E * 4);
    int*    lbin   = (int*)   alloc(LBINS * 4);
    int*    lcur   = (int*)   alloc(LBINS * 4);
    float*  xs     = (float*) alloc((size_t)N * DM * 4);
    float*  xd     = (float*) alloc((size_t)N * DM * 4);
    bf16_t* xij    = (bf16_t*)alloc((size_t)E * DM * 2);
    bf16_t* msg    = (bf16_t*)alloc((size_t)E * DM * 2);
    bf16_t* ft     = (bf16_t*)alloc((size_t)(N + 64) * DM * 2);
    bf16_t* hb     = (bf16_t*)alloc((size_t)(N + 64) * HDIM * 2);
    bf16_t* W1t    = (bf16_t*)alloc((size_t)3 * HDIM * DM * 2);
    bf16_t* W2t    = (bf16_t*)alloc((size_t)3 * DMODEL * HDIM * 2);
    bf16_t* Wedgt  = (bf16_t*)alloc((size_t)3 * DM * DMODEL * 2);
    bf16_t* Wst    = (bf16_t*)alloc((size_t)3 * DM * DMODEL * 2);
    bf16_t* Wdt    = (bf16_t*)alloc((size_t)3 * DM * DMODEL * 2);
    float*  accs   = (float*) alloc(64);
    (void)ws_size; (void)n_in; (void)out_size;

    const int nbScanE = (E + 255) / 256;
    const int nbScanN = (N + 255) / 256;

    // ---- setup (layer-invariant) ----
    k_embed<<<N, 256, 0, stream>>>(an, emb, xb);
    k_edge_geom<<<(E + 255) / 256, 256, 0, stream>>>(r, bl, rn, E);
    for (int l = 0; l < 3; ++l) {
        k_castT<<<dim3(DM / 32, HDIM / 32), 256, 0, stream>>>(
            W1 + (size_t)l * DM * HDIM, W1t + (size_t)l * HDIM * DM, DM, HDIM);
        k_castT<<<dim3(HDIM / 32, DMODEL / 32), 256, 0, stream>>>(
            W2 + (size_t)l * HDIM * DMODEL, W2t + (size_t)l * DMODEL * HDIM,
            HDIM, DMODEL);
        k_castT<<<dim3(DMODEL / 32, DM / 32), 256, 0, stream>>>(
            Wedge + (size_t)l * DMODEL * DM, Wedgt + (size_t)l * DM * DMODEL,
            DMODEL, DM);
        k_castT<<<dim3(DMODEL / 32, DM / 32), 256, 0, stream>>>(
            Wsrc + (size_t)l * DMODEL * DM, Wst + (size_t)l * DM * DMODEL,
            DMODEL, DM);
        k_castT<<<dim3(DMODEL / 32, DM / 32), 256, 0, stream>>>(
            Wdst + (size_t)l * DMODEL * DM, Wdt + (size_t)l * DM * DMODEL,
            DMODEL, DM);
    }
    // triplet CSR by t_dst
    hipMemsetAsync(cnt, 0, (size_t)E * 4, stream);
    k_hist<<<(T + 255) / 256, 256, 0, stream>>>(td, cnt, T);
    k_scan_part<<<nbScanE, 256, 0, stream>>>(cnt, bsum, E);
    k_scan_mid<<<1, 1024, 0, stream>>>(bsum, nbScanE);
    k_scan_final<<<nbScanE, 256, 0, stream>>>(cnt, bsum, rowp, E, T);
    hipMemsetAsync(cnt, 0, (size_t)E * 4, stream);
    k_scatter<<<(T + 255) / 256, 256, 0, stream>>>(ts, td, rowp, cnt, rn,
                                                   packed, T);
    // length-sorted edge order for k_edge_attn
    hipMemsetAsync(lbin, 0, LBINS * 4, stream);
    k_lenhist<<<(E + 255) / 256, 256, 0, stream>>>(rowp, lbin, E);
    k_scan_mid<<<1, 1024, 0, stream>>>(lbin, LBINS);
    hipMemsetAsync(lcur, 0, LBINS * 4, stream);
    k_lenscatter<<<(E + 255) / 256, 256, 0, stream>>>(rowp, lbin, lcur, aord, E);
    // edge CSR by gd
    hipMemsetAsync(ecnt, 0, (size_t)N * 4, stream);
    k_hist<<<(E + 255) / 256, 256, 0, stream>>>(gd, ecnt, E);
    k_scan_part<<<nbScanN, 256, 0, stream>>>(ecnt, bsum, N);
    k_scan_mid<<<1, 1024, 0, stream>>>(bsum, nbScanN);
    k_scan_final<<<nbScanN, 256, 0, stream>>>(ecnt, bsum, erowp, N, E);
    hipMemsetAsync(ecnt, 0, (size_t)N * 4, stream);
    k_escatter<<<(E + 255) / 256, 256, 0, stream>>>(gd, erowp, ecnt, eord, E);

    // ---- layers ----
    for (int l = 0; l < 3; ++l) {
        k_node_proj<<<(N + 63) / 64, 256, 0, stream>>>(
            xb, Wst + (size_t)l * DM * DMODEL, bsrc + l * DM,
            Wdt + (size_t)l * DM * DMODEL, bdst + l * DM, xs, xd, N);
        k_xij<<<(E + 63) / 64, 256, 0, stream>>>(
            bl, Wedgt + (size_t)l * DM * DMODEL, bedge + l * DM,
            xs, xd, gs, gd, xij, E);
        k_edge_attn<<<(E * 16 + 255) / 256, 256, 0, stream>>>(
            xij, packed, rowp, aord, attn + l * DM, msg, E);
        k_aggregate<<<(N * 16 + 255) / 256, 256, 0, stream>>>(
            msg, erowp, eord, ft, N);
        k_ffn1<<<dim3((N + 63) / 64, HDIM / 64), 256, 0, stream>>>(
            ft, W1t + (size_t)l * HDIM * DM, b1 + l * HDIM, hb, N);
        k_ffn2<<<dim3((N + 63) / 64, DMODEL / 64), 256, 0, stream>>>(
            hb, W2t + (size_t)l * DMODEL * HDIM, b2 + l * DMODEL, xb, N);
    }

    // ---- output head ----
    hipMemsetAsync(accs, 0, 4, stream);
    k_out_reduce<<<120, 256, 0, stream>>>(xb, Wfc, accs, N * DMODEL);
    k_out_final<<<1, 1, 0, stream>>>(accs, bfc, (float*)d_out, 1.0f / (float)N);
}

// Round 16
// 966.248 us; speedup vs baseline: 2.1232x; 2.1232x over previous
//
#include <hip/hip_runtime.h>
#include <math.h>

// M3GNet-like GNN forward. N=10000 nodes, E=160000 edges, T=1200000 triplets,
// D=256, DM=64, H=1024, L=3, output = scalar mean energy (fp32).
//
// R15: REVERT R14's length-sort (its k_lenscatter serialized 160k atomics
// onto ~30 bins = 555 us, and the sorted order destroyed xij L2 locality in
// k_edge_attn). Keep the silu-via-v_rcp change (strictly fewer VALU slots).
// Structure = R13 + rcp-silu.

#define DM 64
#define DMODEL 256
#define HDIM 1024

typedef unsigned short bf16_t;
typedef __attribute__((ext_vector_type(8))) short s8v;    // 8 bf16 (4 VGPRs)
typedef __attribute__((ext_vector_type(4))) float f4;     // MFMA acc

__device__ __forceinline__ bf16_t f2bf(float f) {
    unsigned int u = __float_as_uint(f);
    return (bf16_t)((u + 0x7FFFu + ((u >> 16) & 1u)) >> 16);   // RNE
}
__device__ __forceinline__ float bf_lo(unsigned int u) {
    return __uint_as_float(u << 16);
}
__device__ __forceinline__ float bf_hi(unsigned int u) {
    return __uint_as_float(u & 0xFFFF0000u);
}
__device__ __forceinline__ float silu_f(float u) {
    return u * __builtin_amdgcn_rcpf(1.f + __expf(-u));
}

__global__ void k_embed(const int* __restrict__ an, const float* __restrict__ emb,
                        bf16_t* __restrict__ x) {
    int n = blockIdx.x;
    int d = threadIdx.x;
    x[n * DMODEL + d] = f2bf(emb[an[n] * DMODEL + d]);
}

__global__ void k_edge_geom(const float* __restrict__ r, float* __restrict__ bl,
                            float* __restrict__ rn, int E) {
    int e = blockIdx.x * blockDim.x + threadIdx.x;
    if (e >= E) return;
    float a = r[e * 3 + 0], b = r[e * 3 + 1], c = r[e * 3 + 2];
    float l = sqrtf(a * a + b * b + c * c);
    bl[e] = l;
    float inv = 1.0f / l;
    rn[e * 3 + 0] = a * inv;
    rn[e * 3 + 1] = b * inv;
    rn[e * 3 + 2] = c * inv;
}

__global__ void k_hist(const int* __restrict__ idx, int* __restrict__ cnt, int M) {
    int t = blockIdx.x * blockDim.x + threadIdx.x;
    if (t < M) atomicAdd(&cnt[idx[t]], 1);
}

// ---- 3-phase exclusive scan ----
__global__ __launch_bounds__(256) void k_scan_part(
    const int* __restrict__ cnt, int* __restrict__ bsum, int M) {
    __shared__ int sm[4];
    int tid = threadIdx.x;
    int i = blockIdx.x * 256 + tid;
    int v = (i < M) ? cnt[i] : 0;
    for (int off = 32; off > 0; off >>= 1) v += __shfl_xor(v, off, 64);
    if ((tid & 63) == 0) sm[tid >> 6] = v;
    __syncthreads();
    if (tid == 0) bsum[blockIdx.x] = sm[0] + sm[1] + sm[2] + sm[3];
}

__global__ __launch_bounds__(1024) void k_scan_mid(int* __restrict__ bsum, int nb) {
    __shared__ int sm[1024];
    int tid = threadIdx.x;
    int v = (tid < nb) ? bsum[tid] : 0;
    sm[tid] = v;
    __syncthreads();
    for (int off = 1; off < 1024; off <<= 1) {
        int u = (tid >= off) ? sm[tid - off] : 0;
        __syncthreads();
        sm[tid] += u;
        __syncthreads();
    }
    if (tid < nb) bsum[tid] = sm[tid] - v;
}

__global__ __launch_bounds__(256) void k_scan_final(
    const int* __restrict__ cnt, const int* __restrict__ bsum,
    int* __restrict__ rowp, int M, int total) {
    __shared__ int sm[256];
    int tid = threadIdx.x;
    int i = blockIdx.x * 256 + tid;
    int v = (i < M) ? cnt[i] : 0;
    sm[tid] = v;
    __syncthreads();
    for (int off = 1; off < 256; off <<= 1) {
        int u = (tid >= off) ? sm[tid - off] : 0;
        __syncthreads();
        sm[tid] += u;
        __syncthreads();
    }
    if (i < M) rowp[i] = bsum[blockIdx.x] + sm[tid] - v;
    if (i == 0) rowp[M] = total;
}

// scatter triplets into segment order; packed = (src, theta-bits).
__global__ void k_scatter(const int* __restrict__ ts, const int* __restrict__ td,
                          const int* __restrict__ rowp, int* __restrict__ cursor,
                          const float* __restrict__ rn,
                          int2* __restrict__ packed, int T) {
    int t = blockIdx.x * blockDim.x + threadIdx.x;
    if (t >= T) return;
    int a = ts[t], b = td[t];
    float d = rn[a * 3 + 0] * rn[b * 3 + 0]
            + rn[a * 3 + 1] * rn[b * 3 + 1]
            + rn[a * 3 + 2] * rn[b * 3 + 2];
    d = fminf(1.0f, fmaxf(-1.0f, d));
    float th = acosf(d);
    int pos = rowp[b] + atomicAdd(&cursor[b], 1);
    packed[pos] = make_int2(a, __float_as_int(th));
}

__global__ void k_escatter(const int* __restrict__ gd, const int* __restrict__ erowp,
                           int* __restrict__ cursor, int* __restrict__ eord, int E) {
    int e = blockIdx.x * blockDim.x + threadIdx.x;
    if (e >= E) return;
    int n = gd[e];
    int pos = erowp[n] + atomicAdd(&cursor[n], 1);
    eord[pos] = e;
}

// 32x32 tiled transpose + cast: src fp32 [K][Nn] -> dst bf16 [Nn][K].
__global__ __launch_bounds__(256) void k_castT(
    const float* __restrict__ src, bf16_t* __restrict__ dst, int K, int Nn) {
    __shared__ float tile[32][33];
    int k0 = blockIdx.x * 32, n0 = blockIdx.y * 32;
    int tx = threadIdx.x & 31, ty = threadIdx.x >> 5;
    #pragma unroll
    for (int i = 0; i < 4; ++i) {
        int row = ty + i * 8;
        tile[row][tx] = src[(size_t)(k0 + row) * Nn + n0 + tx];
    }
    __syncthreads();
    #pragma unroll
    for (int i = 0; i < 4; ++i) {
        int row = ty + i * 8;
        dst[(size_t)(n0 + row) * K + k0 + tx] = f2bf(tile[tx][row]);
    }
}

// MFMA node_proj: xs = x@Wsrc + bs, xd = x@Wdst + bd (fp32 out).
__global__ __launch_bounds__(256) void k_node_proj(
    const bf16_t* __restrict__ xb,
    const bf16_t* __restrict__ Wst, const float* __restrict__ bs,
    const bf16_t* __restrict__ Wdt, const float* __restrict__ bd,
    float* __restrict__ xs, float* __restrict__ xd, int N) {
    int tid = threadIdx.x;
    int w = tid >> 6, lane = tid & 63;
    int col = lane & 15, quad = lane >> 4;
    int m0 = blockIdx.x * 64 + w * 16;
    f4 as[4] = {{0.f,0.f,0.f,0.f},{0.f,0.f,0.f,0.f},
                {0.f,0.f,0.f,0.f},{0.f,0.f,0.f,0.f}};
    f4 ad[4] = {{0.f,0.f,0.f,0.f},{0.f,0.f,0.f,0.f},
                {0.f,0.f,0.f,0.f},{0.f,0.f,0.f,0.f}};
    #pragma unroll
    for (int k0 = 0; k0 < DMODEL; k0 += 32) {
        s8v a = *(const s8v*)&xb[(size_t)(m0 + col) * DMODEL + k0 + quad * 8];
        #pragma unroll
        for (int t = 0; t < 4; ++t) {
            s8v b1v = *(const s8v*)&Wst[(size_t)(t * 16 + col) * DMODEL + k0 + quad * 8];
            as[t] = __builtin_amdgcn_mfma_f32_16x16x32_bf16(a, b1v, as[t], 0, 0, 0);
            s8v b2v = *(const s8v*)&Wdt[(size_t)(t * 16 + col) * DMODEL + k0 + quad * 8];
            ad[t] = __builtin_amdgcn_mfma_f32_16x16x32_bf16(a, b2v, ad[t], 0, 0, 0);
        }
    }
    #pragma unroll
    for (int t = 0; t < 4; ++t) {
        int c = t * 16 + col;
        float bsv = bs[c], bdv = bd[c];
        #pragma unroll
        for (int r = 0; r < 4; ++r) {
            int m = m0 + quad * 4 + r;
            if (m < N) {
                xs[(size_t)m * DM + c] = as[t][r] + bsv;
                xd[(size_t)m * DM + c] = ad[t][r] + bdv;
            }
        }
    }
}

// MFMA k_xij: xij[e][c] = (RBF(bl[e]) @ Wedge)[c] + xs[gs[e]][c] + xd[gd[e]][c] + be[c]
__global__ __launch_bounds__(256) void k_xij(
    const float* __restrict__ bl, const bf16_t* __restrict__ Wedgt,
    const float* __restrict__ be,
    const float* __restrict__ xs, const float* __restrict__ xd,
    const int* __restrict__ gs, const int* __restrict__ gd,
    bf16_t* __restrict__ xij, int E) {
    int tid = threadIdx.x;
    int w = tid >> 6, lane = tid & 63;
    int col = lane & 15, quad = lane >> 4;
    int m0 = blockIdx.x * 64 + w * 16;
    const float step = 8.0f / 255.0f;
    const float gamma = (255.0f / 8.0f) * (255.0f / 8.0f);
    int me = m0 + col;
    float blv = (me < E) ? bl[me] : 0.f;
    f4 acc[4] = {{0.f,0.f,0.f,0.f},{0.f,0.f,0.f,0.f},
                 {0.f,0.f,0.f,0.f},{0.f,0.f,0.f,0.f}};
    #pragma unroll
    for (int k0 = 0; k0 < DMODEL; k0 += 32) {
        s8v a;
        #pragma unroll
        for (int j = 0; j < 8; ++j) {
            float c = (float)(k0 + quad * 8 + j) * step;
            float dd = blv - c;
            a[j] = (short)f2bf(__expf(-gamma * dd * dd));
        }
        #pragma unroll
        for (int t = 0; t < 4; ++t) {
            s8v b = *(const s8v*)&Wedgt[(size_t)(t * 16 + col) * DMODEL + k0 + quad * 8];
            acc[t] = __builtin_amdgcn_mfma_f32_16x16x32_bf16(a, b, acc[t], 0, 0, 0);
        }
    }
    #pragma unroll
    for (int r = 0; r < 4; ++r) {
        int e = m0 + quad * 4 + r;
        if (e >= E) continue;
        int s = gs[e], d2 = gd[e];
        #pragma unroll
        for (int t = 0; t < 4; ++t) {
            int c = t * 16 + col;
            float v = acc[t][r] + xs[(size_t)s * DM + c] + xd[(size_t)d2 * DM + c] + be[c];
            xij[(size_t)e * DM + c] = f2bf(v);
        }
    }
}

// Fused logit+softmax+attend: 16-lane group per edge, lane q = channels
// [4q, 4q+4). T_k = __cosf(k*theta); silu via v_rcp; no running max.
__global__ __launch_bounds__(256) void k_edge_attn(
    const bf16_t* __restrict__ xij, const int2* __restrict__ packed,
    const int* __restrict__ rowp, const float* __restrict__ attn_l,
    bf16_t* __restrict__ msg, int E) {
    int gtid = blockIdx.x * 256 + threadIdx.x;
    int e = gtid >> 4;
    if (e >= E) return;
    int q = gtid & 15;
    int beg = rowp[e], end = rowp[e + 1];
    float a0 = 0.f, a1 = 0.f, a2 = 0.f, a3 = 0.f;
    if (beg < end) {
        uint2 ue = *(const uint2*)&xij[(size_t)e * DM + q * 4];
        float xe0 = bf_lo(ue.x), xe1 = bf_hi(ue.x);
        float xe2 = bf_lo(ue.y), xe3 = bf_hi(ue.y);
        float4 at = *(const float4*)&attn_l[q * 4];
        float kf = (float)(4 * q);
        float den = 0.f;
        for (int p = beg; p < end; ++p) {
            int2 pk = packed[p];
            int s = pk.x;
            float th = __int_as_float(pk.y);
            uint2 us = *(const uint2*)&xij[(size_t)s * DM + q * 4];
            float xs0 = bf_lo(us.x), xs1 = bf_hi(us.x);
            float xs2 = bf_lo(us.y), xs3 = bf_hi(us.y);
            float u0 = __cosf(kf * th) + xs0 + xe0;
            float u1 = __cosf((kf + 1.f) * th) + xs1 + xe1;
            float u2 = __cosf((kf + 2.f) * th) + xs2 + xe2;
            float u3 = __cosf((kf + 3.f) * th) + xs3 + xe3;
            float s0 = silu_f(u0), s1 = silu_f(u1);
            float s2 = silu_f(u2), s3 = silu_f(u3);
            float partial = fmaf(s0, at.x, fmaf(s1, at.y,
                            fmaf(s2, at.z, s3 * at.w)));
            #pragma unroll
            for (int off = 1; off < 16; off <<= 1)
                partial += __shfl_xor(partial, off, 64);
            float wg = __expf(partial);
            den += wg;
            a0 = fmaf(wg, xs0, a0);
            a1 = fmaf(wg, xs1, a1);
            a2 = fmaf(wg, xs2, a2);
            a3 = fmaf(wg, xs3, a3);
        }
        float inv = 1.f / den;
        a0 *= inv; a1 *= inv; a2 *= inv; a3 *= inv;
    }
    ushort4 o = {f2bf(a0), f2bf(a1), f2bf(a2), f2bf(a3)};
    *(ushort4*)&msg[(size_t)e * DM + q * 4] = o;
}

// thread per (node, channel-quad): sum bf16 msg -> bf16 ft.
__global__ __launch_bounds__(256) void k_aggregate(
    const bf16_t* __restrict__ msg, const int* __restrict__ erowp,
    const int* __restrict__ eord, bf16_t* __restrict__ ft, int N) {
    int gtid = blockIdx.x * 256 + threadIdx.x;
    int n = gtid >> 4;
    if (n >= N) return;
    int quad = gtid & 15;
    int beg = erowp[n], end = erowp[n + 1];
    float a0 = 0.f, a1 = 0.f, a2 = 0.f, a3 = 0.f;
    for (int j = beg; j < end; ++j) {
        uint2 uv = *(const uint2*)&msg[(size_t)eord[j] * DM + quad * 4];
        a0 += bf_lo(uv.x); a1 += bf_hi(uv.x);
        a2 += bf_lo(uv.y); a3 += bf_hi(uv.y);
    }
    ushort4 o = {f2bf(a0), f2bf(a1), f2bf(a2), f2bf(a3)};
    *(ushort4*)&ft[(size_t)n * DM + quad * 4] = o;
}

// MFMA ffn1: h = silu(ft(bf16) @ W1 + b1), h bf16. grid (157, 16).
__global__ __launch_bounds__(256) void k_ffn1(
    const bf16_t* __restrict__ ft, const bf16_t* __restrict__ W1t,
    const float* __restrict__ b1, bf16_t* __restrict__ h, int N) {
    int tid = threadIdx.x;
    int w = tid >> 6, lane = tid & 63;
    int col = lane & 15, quad = lane >> 4;
    int m0 = blockIdx.x * 64 + w * 16;
    int c0 = blockIdx.y * 64;
    f4 acc[4] = {{0.f,0.f,0.f,0.f},{0.f,0.f,0.f,0.f},
                 {0.f,0.f,0.f,0.f},{0.f,0.f,0.f,0.f}};
    #pragma unroll
    for (int k0 = 0; k0 < DM; k0 += 32) {
        s8v a = *(const s8v*)&ft[(size_t)(m0 + col) * DM + k0 + quad * 8];
        #pragma unroll
        for (int t = 0; t < 4; ++t) {
            s8v b = *(const s8v*)&W1t[(size_t)(c0 + t * 16 + col) * DM + k0 + quad * 8];
            acc[t] = __builtin_amdgcn_mfma_f32_16x16x32_bf16(a, b, acc[t], 0, 0, 0);
        }
    }
    #pragma unroll
    for (int t = 0; t < 4; ++t) {
        int c = c0 + t * 16 + col;
        float bb = b1[c];
        #pragma unroll
        for (int r = 0; r < 4; ++r) {
            int m = m0 + quad * 4 + r;
            if (m < N) {
                float v = acc[t][r] + bb;
                h[(size_t)m * HDIM + c] = f2bf(silu_f(v));
            }
        }
    }
}

// MFMA ffn2: x = h(bf16) @ W2 + b2 (bf16 out). grid (157, 4).
__global__ __launch_bounds__(256) void k_ffn2(
    const bf16_t* __restrict__ h, const bf16_t* __restrict__ W2t,
    const float* __restrict__ b2, bf16_t* __restrict__ x, int N) {
    int tid = threadIdx.x;
    int w = tid >> 6, lane = tid & 63;
    int col = lane & 15, quad = lane >> 4;
    int m0 = blockIdx.x * 64 + w * 16;
    int c0 = blockIdx.y * 64;
    f4 acc[4] = {{0.f,0.f,0.f,0.f},{0.f,0.f,0.f,0.f},
                 {0.f,0.f,0.f,0.f},{0.f,0.f,0.f,0.f}};
    for (int k0 = 0; k0 < HDIM; k0 += 32) {
        s8v a = *(const s8v*)&h[(size_t)(m0 + col) * HDIM + k0 + quad * 8];
        #pragma unroll
        for (int t = 0; t < 4; ++t) {
            s8v b = *(const s8v*)&W2t[(size_t)(c0 + t * 16 + col) * HDIM + k0 + quad * 8];
            acc[t] = __builtin_amdgcn_mfma_f32_16x16x32_bf16(a, b, acc[t], 0, 0, 0);
        }
    }
    #pragma unroll
    for (int t = 0; t < 4; ++t) {
        int c = c0 + t * 16 + col;
        float bb = b2[c];
        #pragma unroll
        for (int r = 0; r < 4; ++r) {
            int m = m0 + quad * 4 + r;
            if (m < N) x[(size_t)m * DMODEL + c] = f2bf(acc[t][r] + bb);
        }
    }
}

// grid-stride dot over bf16 x, one atomic per block.
__global__ __launch_bounds__(256) void k_out_reduce(
    const bf16_t* __restrict__ x, const float* __restrict__ Wfc,
    float* __restrict__ acc, int NT) {
    __shared__ float sm[4];
    int tid = threadIdx.x;
    float v = 0.f;
    int np = NT / 2;
    const unsigned int* xp = (const unsigned int*)x;
    for (int i = blockIdx.x * blockDim.x + tid; i < np; i += gridDim.x * blockDim.x) {
        unsigned int u = xp[i];
        int c = (2 * i) & (DMODEL - 1);
        v = fmaf(bf_lo(u), Wfc[c], v);
        v = fmaf(bf_hi(u), Wfc[c + 1], v);
    }
    for (int off = 32; off > 0; off >>= 1) v += __shfl_xor(v, off, 64);
    if ((tid & 63) == 0) sm[tid >> 6] = v;
    __syncthreads();
    if (tid == 0) {
        float s = sm[0] + sm[1] + sm[2] + sm[3];
        atomicAdd(acc, s);
    }
}

__global__ void k_out_final(const float* __restrict__ acc, const float* __restrict__ bfc,
                            float* __restrict__ out, float invN) {
    out[0] = acc[0] * invN + bfc[0];
}

extern "C" void kernel_launch(void* const* d_in, const int* in_sizes, int n_in,
                              void* d_out, int out_size, void* d_ws, size_t ws_size,
                              hipStream_t stream) {
    const int*   an    = (const int*)d_in[0];
    const int*   gs    = (const int*)d_in[1];
    const int*   gd    = (const int*)d_in[2];
    const int*   ts    = (const int*)d_in[3];
    const int*   td    = (const int*)d_in[4];
    const float* r     = (const float*)d_in[5];
    const float* emb   = (const float*)d_in[6];
    const float* Wsrc  = (const float*)d_in[7];
    const float* bsrc  = (const float*)d_in[8];
    const float* Wdst  = (const float*)d_in[9];
    const float* bdst  = (const float*)d_in[10];
    const float* Wedge = (const float*)d_in[11];
    const float* bedge = (const float*)d_in[12];
    const float* attn  = (const float*)d_in[13];
    const float* W1    = (const float*)d_in[14];
    const float* b1    = (const float*)d_in[15];
    const float* W2    = (const float*)d_in[16];
    const float* b2    = (const float*)d_in[17];
    const float* Wfc   = (const float*)d_in[18];
    const float* bfc   = (const float*)d_in[19];

    const int N = in_sizes[0];
    const int E = in_sizes[1];
    const int T = in_sizes[3];

    char* w = (char*)d_ws;
    size_t off = 0;
    auto alloc = [&](size_t bytes) {
        void* p = w + off;
        off += (bytes + 255) & ~(size_t)255;
        return p;
    };
    bf16_t* xb     = (bf16_t*)alloc((size_t)(N + 64) * DMODEL * 2);
    float*  rn     = (float*) alloc((size_t)E * 3 * 4);
    float*  bl     = (float*) alloc(((size_t)E + 64) * 4);
    int*    cnt    = (int*)   alloc((size_t)E * 4);
    int*    rowp   = (int*)   alloc(((size_t)E + 1) * 4);
    int*    bsum   = (int*)   alloc(4096);
    int2*   packed = (int2*)  alloc((size_t)T * 8);
    int*    ecnt   = (int*)   alloc((size_t)N * 4);
    int*    erowp  = (int*)   alloc(((size_t)N + 1) * 4);
    int*    eord   = (int*)   alloc((size_t)E * 4);
    float*  xs     = (float*) alloc((size_t)N * DM * 4);
    float*  xd     = (float*) alloc((size_t)N * DM * 4);
    bf16_t* xij    = (bf16_t*)alloc((size_t)E * DM * 2);
    bf16_t* msg    = (bf16_t*)alloc((size_t)E * DM * 2);
    bf16_t* ft     = (bf16_t*)alloc((size_t)(N + 64) * DM * 2);
    bf16_t* hb     = (bf16_t*)alloc((size_t)(N + 64) * HDIM * 2);
    bf16_t* W1t    = (bf16_t*)alloc((size_t)3 * HDIM * DM * 2);
    bf16_t* W2t    = (bf16_t*)alloc((size_t)3 * DMODEL * HDIM * 2);
    bf16_t* Wedgt  = (bf16_t*)alloc((size_t)3 * DM * DMODEL * 2);
    bf16_t* Wst    = (bf16_t*)alloc((size_t)3 * DM * DMODEL * 2);
    bf16_t* Wdt    = (bf16_t*)alloc((size_t)3 * DM * DMODEL * 2);
    float*  accs   = (float*) alloc(64);
    (void)ws_size; (void)n_in; (void)out_size;

    const int nbScanE = (E + 255) / 256;
    const int nbScanN = (N + 255) / 256;

    // ---- setup (layer-invariant) ----
    k_embed<<<N, 256, 0, stream>>>(an, emb, xb);
    k_edge_geom<<<(E + 255) / 256, 256, 0, stream>>>(r, bl, rn, E);
    for (int l = 0; l < 3; ++l) {
        k_castT<<<dim3(DM / 32, HDIM / 32), 256, 0, stream>>>(
            W1 + (size_t)l * DM * HDIM, W1t + (size_t)l * HDIM * DM, DM, HDIM);
        k_castT<<<dim3(HDIM / 32, DMODEL / 32), 256, 0, stream>>>(
            W2 + (size_t)l * HDIM * DMODEL, W2t + (size_t)l * DMODEL * HDIM,
            HDIM, DMODEL);
        k_castT<<<dim3(DMODEL / 32, DM / 32), 256, 0, stream>>>(
            Wedge + (size_t)l * DMODEL * DM, Wedgt + (size_t)l * DM * DMODEL,
            DMODEL, DM);
        k_castT<<<dim3(DMODEL / 32, DM / 32), 256, 0, stream>>>(
            Wsrc + (size_t)l * DMODEL * DM, Wst + (size_t)l * DM * DMODEL,
            DMODEL, DM);
        k_castT<<<dim3(DMODEL / 32, DM / 32), 256, 0, stream>>>(
            Wdst + (size_t)l * DMODEL * DM, Wdt + (size_t)l * DM * DMODEL,
            DMODEL, DM);
    }
    // triplet CSR by t_dst
    hipMemsetAsync(cnt, 0, (size_t)E * 4, stream);
    k_hist<<<(T + 255) / 256, 256, 0, stream>>>(td, cnt, T);
    k_scan_part<<<nbScanE, 256, 0, stream>>>(cnt, bsum, E);
    k_scan_mid<<<1, 1024, 0, stream>>>(bsum, nbScanE);
    k_scan_final<<<nbScanE, 256, 0, stream>>>(cnt, bsum, rowp, E, T);
    hipMemsetAsync(cnt, 0, (size_t)E * 4, stream);
    k_scatter<<<(T + 255) / 256, 256, 0, stream>>>(ts, td, rowp, cnt, rn,
                                                   packed, T);
    // edge CSR by gd
    hipMemsetAsync(ecnt, 0, (size_t)N * 4, stream);
    k_hist<<<(E + 255) / 256, 256, 0, stream>>>(gd, ecnt, E);
    k_scan_part<<<nbScanN, 256, 0, stream>>>(ecnt, bsum, N);
    k_scan_mid<<<1, 1024, 0, stream>>>(bsum, nbScanN);
    k_scan_final<<<nbScanN, 256, 0, stream>>>(ecnt, bsum, erowp, N, E);
    hipMemsetAsync(ecnt, 0, (size_t)N * 4, stream);
    k_escatter<<<(E + 255) / 256, 256, 0, stream>>>(gd, erowp, ecnt, eord, E);

    // ---- layers ----
    for (int l = 0; l < 3; ++l) {
        k_node_proj<<<(N + 63) / 64, 256, 0, stream>>>(
            xb, Wst + (size_t)l * DM * DMODEL, bsrc + l * DM,
            Wdt + (size_t)l * DM * DMODEL, bdst + l * DM, xs, xd, N);
        k_xij<<<(E + 63) / 64, 256, 0, stream>>>(
            bl, Wedgt + (size_t)l * DM * DMODEL, bedge + l * DM,
            xs, xd, gs, gd, xij, E);
        k_edge_attn<<<(E * 16 + 255) / 256, 256, 0, stream>>>(
            xij, packed, rowp, attn + l * DM, msg, E);
        k_aggregate<<<(N * 16 + 255) / 256, 256, 0, stream>>>(
            msg, erowp, eord, ft, N);
        k_ffn1<<<dim3((N + 63) / 64, HDIM / 64), 256, 0, stream>>>(
            ft, W1t + (size_t)l * HDIM * DM, b1 + l * HDIM, hb, N);
        k_ffn2<<<dim3((N + 63) / 64, DMODEL / 64), 256, 0, stream>>>(
            hb, W2t + (size_t)l * DMODEL * HDIM, b2 + l * DMODEL, xb, N);
    }

    // ---- output head ----
    hipMemsetAsync(accs, 0, 4, stream);
    k_out_reduce<<<120, 256, 0, stream>>>(xb, Wfc, accs, N * DMODEL);
    k_out_final<<<1, 1, 0, stream>>>(accs, bfc, (float*)d_out, 1.0f / (float)N);
}

// Round 17
// 959.912 us; speedup vs baseline: 2.1372x; 1.0066x over previous
//
#include <hip/hip_runtime.h>
#include <math.h>

// M3GNet-like GNN forward. N=10000 nodes, E=160000 edges, T=1200000 triplets,
// D=256, DM=64, H=1024, L=3, output = scalar mean energy (fp32).
//
// R16: software-pipeline k_edge_attn's segment loop. The per-iteration
// packed[p] -> xij[src] dependent-gather chain (~200-400 cyc L2 latency)
// was only half-hidden (VALUBusy 78%, measured 71us vs ~33us issue floor).
// Depth-2 prefetch of packed, depth-1 prefetch of the src row: both loads
// issue under the previous triplet's ~180-cyc compute body.

#define DM 64
#define DMODEL 256
#define HDIM 1024

typedef unsigned short bf16_t;
typedef __attribute__((ext_vector_type(8))) short s8v;    // 8 bf16 (4 VGPRs)
typedef __attribute__((ext_vector_type(4))) float f4;     // MFMA acc

__device__ __forceinline__ bf16_t f2bf(float f) {
    unsigned int u = __float_as_uint(f);
    return (bf16_t)((u + 0x7FFFu + ((u >> 16) & 1u)) >> 16);   // RNE
}
__device__ __forceinline__ float bf_lo(unsigned int u) {
    return __uint_as_float(u << 16);
}
__device__ __forceinline__ float bf_hi(unsigned int u) {
    return __uint_as_float(u & 0xFFFF0000u);
}
__device__ __forceinline__ float silu_f(float u) {
    return u * __builtin_amdgcn_rcpf(1.f + __expf(-u));
}

__global__ void k_embed(const int* __restrict__ an, const float* __restrict__ emb,
                        bf16_t* __restrict__ x) {
    int n = blockIdx.x;
    int d = threadIdx.x;
    x[n * DMODEL + d] = f2bf(emb[an[n] * DMODEL + d]);
}

__global__ void k_edge_geom(const float* __restrict__ r, float* __restrict__ bl,
                            float* __restrict__ rn, int E) {
    int e = blockIdx.x * blockDim.x + threadIdx.x;
    if (e >= E) return;
    float a = r[e * 3 + 0], b = r[e * 3 + 1], c = r[e * 3 + 2];
    float l = sqrtf(a * a + b * b + c * c);
    bl[e] = l;
    float inv = 1.0f / l;
    rn[e * 3 + 0] = a * inv;
    rn[e * 3 + 1] = b * inv;
    rn[e * 3 + 2] = c * inv;
}

__global__ void k_hist(const int* __restrict__ idx, int* __restrict__ cnt, int M) {
    int t = blockIdx.x * blockDim.x + threadIdx.x;
    if (t < M) atomicAdd(&cnt[idx[t]], 1);
}

// ---- 3-phase exclusive scan ----
__global__ __launch_bounds__(256) void k_scan_part(
    const int* __restrict__ cnt, int* __restrict__ bsum, int M) {
    __shared__ int sm[4];
    int tid = threadIdx.x;
    int i = blockIdx.x * 256 + tid;
    int v = (i < M) ? cnt[i] : 0;
    for (int off = 32; off > 0; off >>= 1) v += __shfl_xor(v, off, 64);
    if ((tid & 63) == 0) sm[tid >> 6] = v;
    __syncthreads();
    if (tid == 0) bsum[blockIdx.x] = sm[0] + sm[1] + sm[2] + sm[3];
}

__global__ __launch_bounds__(1024) void k_scan_mid(int* __restrict__ bsum, int nb) {
    __shared__ int sm[1024];
    int tid = threadIdx.x;
    int v = (tid < nb) ? bsum[tid] : 0;
    sm[tid] = v;
    __syncthreads();
    for (int off = 1; off < 1024; off <<= 1) {
        int u = (tid >= off) ? sm[tid - off] : 0;
        __syncthreads();
        sm[tid] += u;
        __syncthreads();
    }
    if (tid < nb) bsum[tid] = sm[tid] - v;
}

__global__ __launch_bounds__(256) void k_scan_final(
    const int* __restrict__ cnt, const int* __restrict__ bsum,
    int* __restrict__ rowp, int M, int total) {
    __shared__ int sm[256];
    int tid = threadIdx.x;
    int i = blockIdx.x * 256 + tid;
    int v = (i < M) ? cnt[i] : 0;
    sm[tid] = v;
    __syncthreads();
    for (int off = 1; off < 256; off <<= 1) {
        int u = (tid >= off) ? sm[tid - off] : 0;
        __syncthreads();
        sm[tid] += u;
        __syncthreads();
    }
    if (i < M) rowp[i] = bsum[blockIdx.x] + sm[tid] - v;
    if (i == 0) rowp[M] = total;
}

// scatter triplets into segment order; packed = (src, theta-bits).
__global__ void k_scatter(const int* __restrict__ ts, const int* __restrict__ td,
                          const int* __restrict__ rowp, int* __restrict__ cursor,
                          const float* __restrict__ rn,
                          int2* __restrict__ packed, int T) {
    int t = blockIdx.x * blockDim.x + threadIdx.x;
    if (t >= T) return;
    int a = ts[t], b = td[t];
    float d = rn[a * 3 + 0] * rn[b * 3 + 0]
            + rn[a * 3 + 1] * rn[b * 3 + 1]
            + rn[a * 3 + 2] * rn[b * 3 + 2];
    d = fminf(1.0f, fmaxf(-1.0f, d));
    float th = acosf(d);
    int pos = rowp[b] + atomicAdd(&cursor[b], 1);
    packed[pos] = make_int2(a, __float_as_int(th));
}

__global__ void k_escatter(const int* __restrict__ gd, const int* __restrict__ erowp,
                           int* __restrict__ cursor, int* __restrict__ eord, int E) {
    int e = blockIdx.x * blockDim.x + threadIdx.x;
    if (e >= E) return;
    int n = gd[e];
    int pos = erowp[n] + atomicAdd(&cursor[n], 1);
    eord[pos] = e;
}

// 32x32 tiled transpose + cast: src fp32 [K][Nn] -> dst bf16 [Nn][K].
__global__ __launch_bounds__(256) void k_castT(
    const float* __restrict__ src, bf16_t* __restrict__ dst, int K, int Nn) {
    __shared__ float tile[32][33];
    int k0 = blockIdx.x * 32, n0 = blockIdx.y * 32;
    int tx = threadIdx.x & 31, ty = threadIdx.x >> 5;
    #pragma unroll
    for (int i = 0; i < 4; ++i) {
        int row = ty + i * 8;
        tile[row][tx] = src[(size_t)(k0 + row) * Nn + n0 + tx];
    }
    __syncthreads();
    #pragma unroll
    for (int i = 0; i < 4; ++i) {
        int row = ty + i * 8;
        dst[(size_t)(n0 + row) * K + k0 + tx] = f2bf(tile[tx][row]);
    }
}

// MFMA node_proj: xs = x@Wsrc + bs, xd = x@Wdst + bd (fp32 out).
__global__ __launch_bounds__(256) void k_node_proj(
    const bf16_t* __restrict__ xb,
    const bf16_t* __restrict__ Wst, const float* __restrict__ bs,
    const bf16_t* __restrict__ Wdt, const float* __restrict__ bd,
    float* __restrict__ xs, float* __restrict__ xd, int N) {
    int tid = threadIdx.x;
    int w = tid >> 6, lane = tid & 63;
    int col = lane & 15, quad = lane >> 4;
    int m0 = blockIdx.x * 64 + w * 16;
    f4 as[4] = {{0.f,0.f,0.f,0.f},{0.f,0.f,0.f,0.f},
                {0.f,0.f,0.f,0.f},{0.f,0.f,0.f,0.f}};
    f4 ad[4] = {{0.f,0.f,0.f,0.f},{0.f,0.f,0.f,0.f},
                {0.f,0.f,0.f,0.f},{0.f,0.f,0.f,0.f}};
    #pragma unroll
    for (int k0 = 0; k0 < DMODEL; k0 += 32) {
        s8v a = *(const s8v*)&xb[(size_t)(m0 + col) * DMODEL + k0 + quad * 8];
        #pragma unroll
        for (int t = 0; t < 4; ++t) {
            s8v b1v = *(const s8v*)&Wst[(size_t)(t * 16 + col) * DMODEL + k0 + quad * 8];
            as[t] = __builtin_amdgcn_mfma_f32_16x16x32_bf16(a, b1v, as[t], 0, 0, 0);
            s8v b2v = *(const s8v*)&Wdt[(size_t)(t * 16 + col) * DMODEL + k0 + quad * 8];
            ad[t] = __builtin_amdgcn_mfma_f32_16x16x32_bf16(a, b2v, ad[t], 0, 0, 0);
        }
    }
    #pragma unroll
    for (int t = 0; t < 4; ++t) {
        int c = t * 16 + col;
        float bsv = bs[c], bdv = bd[c];
        #pragma unroll
        for (int r = 0; r < 4; ++r) {
            int m = m0 + quad * 4 + r;
            if (m < N) {
                xs[(size_t)m * DM + c] = as[t][r] + bsv;
                xd[(size_t)m * DM + c] = ad[t][r] + bdv;
            }
        }
    }
}

// MFMA k_xij: xij[e][c] = (RBF(bl[e]) @ Wedge)[c] + xs[gs[e]][c] + xd[gd[e]][c] + be[c]
__global__ __launch_bounds__(256) void k_xij(
    const float* __restrict__ bl, const bf16_t* __restrict__ Wedgt,
    const float* __restrict__ be,
    const float* __restrict__ xs, const float* __restrict__ xd,
    const int* __restrict__ gs, const int* __restrict__ gd,
    bf16_t* __restrict__ xij, int E) {
    int tid = threadIdx.x;
    int w = tid >> 6, lane = tid & 63;
    int col = lane & 15, quad = lane >> 4;
    int m0 = blockIdx.x * 64 + w * 16;
    const float step = 8.0f / 255.0f;
    const float gamma = (255.0f / 8.0f) * (255.0f / 8.0f);
    int me = m0 + col;
    float blv = (me < E) ? bl[me] : 0.f;
    f4 acc[4] = {{0.f,0.f,0.f,0.f},{0.f,0.f,0.f,0.f},
                 {0.f,0.f,0.f,0.f},{0.f,0.f,0.f,0.f}};
    #pragma unroll
    for (int k0 = 0; k0 < DMODEL; k0 += 32) {
        s8v a;
        #pragma unroll
        for (int j = 0; j < 8; ++j) {
            float c = (float)(k0 + quad * 8 + j) * step;
            float dd = blv - c;
            a[j] = (short)f2bf(__expf(-gamma * dd * dd));
        }
        #pragma unroll
        for (int t = 0; t < 4; ++t) {
            s8v b = *(const s8v*)&Wedgt[(size_t)(t * 16 + col) * DMODEL + k0 + quad * 8];
            acc[t] = __builtin_amdgcn_mfma_f32_16x16x32_bf16(a, b, acc[t], 0, 0, 0);
        }
    }
    #pragma unroll
    for (int r = 0; r < 4; ++r) {
        int e = m0 + quad * 4 + r;
        if (e >= E) continue;
        int s = gs[e], d2 = gd[e];
        #pragma unroll
        for (int t = 0; t < 4; ++t) {
            int c = t * 16 + col;
            float v = acc[t][r] + xs[(size_t)s * DM + c] + xd[(size_t)d2 * DM + c] + be[c];
            xij[(size_t)e * DM + c] = f2bf(v);
        }
    }
}

// Fused logit+softmax+attend: 16-lane group per edge, lane q = channels
// [4q, 4q+4). Software-pipelined: packed prefetched depth-2, src row depth-1.
__global__ __launch_bounds__(256) void k_edge_attn(
    const bf16_t* __restrict__ xij, const int2* __restrict__ packed,
    const int* __restrict__ rowp, const float* __restrict__ attn_l,
    bf16_t* __restrict__ msg, int E) {
    int gtid = blockIdx.x * 256 + threadIdx.x;
    int e = gtid >> 4;
    if (e >= E) return;
    int q = gtid & 15;
    int beg = rowp[e], end = rowp[e + 1];
    float a0 = 0.f, a1 = 0.f, a2 = 0.f, a3 = 0.f;
    if (beg < end) {
        uint2 ue = *(const uint2*)&xij[(size_t)e * DM + q * 4];
        float xe0 = bf_lo(ue.x), xe1 = bf_hi(ue.x);
        float xe2 = bf_lo(ue.y), xe3 = bf_hi(ue.y);
        float4 at = *(const float4*)&attn_l[q * 4];
        float kf = (float)(4 * q);
        float den = 0.f;
        // pipeline priming
        int2 pk0 = packed[beg];
        int2 pk1 = (beg + 1 < end) ? packed[beg + 1] : pk0;
        uint2 us0 = *(const uint2*)&xij[(size_t)pk0.x * DM + q * 4];
        for (int p = beg; p < end; ++p) {
            int2 pkc = pk0;
            uint2 usc = us0;
            if (p + 1 < end) {
                us0 = *(const uint2*)&xij[(size_t)pk1.x * DM + q * 4];
                pk0 = pk1;
                if (p + 2 < end) pk1 = packed[p + 2];
            }
            float th = __int_as_float(pkc.y);
            float xs0 = bf_lo(usc.x), xs1 = bf_hi(usc.x);
            float xs2 = bf_lo(usc.y), xs3 = bf_hi(usc.y);
            float u0 = __cosf(kf * th) + xs0 + xe0;
            float u1 = __cosf((kf + 1.f) * th) + xs1 + xe1;
            float u2 = __cosf((kf + 2.f) * th) + xs2 + xe2;
            float u3 = __cosf((kf + 3.f) * th) + xs3 + xe3;
            float s0 = silu_f(u0), s1 = silu_f(u1);
            float s2 = silu_f(u2), s3 = silu_f(u3);
            float partial = fmaf(s0, at.x, fmaf(s1, at.y,
                            fmaf(s2, at.z, s3 * at.w)));
            #pragma unroll
            for (int off = 1; off < 16; off <<= 1)
                partial += __shfl_xor(partial, off, 64);
            float wg = __expf(partial);
            den += wg;
            a0 = fmaf(wg, xs0, a0);
            a1 = fmaf(wg, xs1, a1);
            a2 = fmaf(wg, xs2, a2);
            a3 = fmaf(wg, xs3, a3);
        }
        float inv = 1.f / den;
        a0 *= inv; a1 *= inv; a2 *= inv; a3 *= inv;
    }
    ushort4 o = {f2bf(a0), f2bf(a1), f2bf(a2), f2bf(a3)};
    *(ushort4*)&msg[(size_t)e * DM + q * 4] = o;
}

// thread per (node, channel-quad): sum bf16 msg -> bf16 ft.
__global__ __launch_bounds__(256) void k_aggregate(
    const bf16_t* __restrict__ msg, const int* __restrict__ erowp,
    const int* __restrict__ eord, bf16_t* __restrict__ ft, int N) {
    int gtid = blockIdx.x * 256 + threadIdx.x;
    int n = gtid >> 4;
    if (n >= N) return;
    int quad = gtid & 15;
    int beg = erowp[n], end = erowp[n + 1];
    float a0 = 0.f, a1 = 0.f, a2 = 0.f, a3 = 0.f;
    for (int j = beg; j < end; ++j) {
        uint2 uv = *(const uint2*)&msg[(size_t)eord[j] * DM + quad * 4];
        a0 += bf_lo(uv.x); a1 += bf_hi(uv.x);
        a2 += bf_lo(uv.y); a3 += bf_hi(uv.y);
    }
    ushort4 o = {f2bf(a0), f2bf(a1), f2bf(a2), f2bf(a3)};
    *(ushort4*)&ft[(size_t)n * DM + quad * 4] = o;
}

// MFMA ffn1: h = silu(ft(bf16) @ W1 + b1), h bf16. grid (157, 16).
__global__ __launch_bounds__(256) void k_ffn1(
    const bf16_t* __restrict__ ft, const bf16_t* __restrict__ W1t,
    const float* __restrict__ b1, bf16_t* __restrict__ h, int N) {
    int tid = threadIdx.x;
    int w = tid >> 6, lane = tid & 63;
    int col = lane & 15, quad = lane >> 4;
    int m0 = blockIdx.x * 64 + w * 16;
    int c0 = blockIdx.y * 64;
    f4 acc[4] = {{0.f,0.f,0.f,0.f},{0.f,0.f,0.f,0.f},
                 {0.f,0.f,0.f,0.f},{0.f,0.f,0.f,0.f}};
    #pragma unroll
    for (int k0 = 0; k0 < DM; k0 += 32) {
        s8v a = *(const s8v*)&ft[(size_t)(m0 + col) * DM + k0 + quad * 8];
        #pragma unroll
        for (int t = 0; t < 4; ++t) {
            s8v b = *(const s8v*)&W1t[(size_t)(c0 + t * 16 + col) * DM + k0 + quad * 8];
            acc[t] = __builtin_amdgcn_mfma_f32_16x16x32_bf16(a, b, acc[t], 0, 0, 0);
        }
    }
    #pragma unroll
    for (int t = 0; t < 4; ++t) {
        int c = c0 + t * 16 + col;
        float bb = b1[c];
        #pragma unroll
        for (int r = 0; r < 4; ++r) {
            int m = m0 + quad * 4 + r;
            if (m < N) {
                float v = acc[t][r] + bb;
                h[(size_t)m * HDIM + c] = f2bf(silu_f(v));
            }
        }
    }
}

// MFMA ffn2: x = h(bf16) @ W2 + b2 (bf16 out). grid (157, 4).
__global__ __launch_bounds__(256) void k_ffn2(
    const bf16_t* __restrict__ h, const bf16_t* __restrict__ W2t,
    const float* __restrict__ b2, bf16_t* __restrict__ x, int N) {
    int tid = threadIdx.x;
    int w = tid >> 6, lane = tid & 63;
    int col = lane & 15, quad = lane >> 4;
    int m0 = blockIdx.x * 64 + w * 16;
    int c0 = blockIdx.y * 64;
    f4 acc[4] = {{0.f,0.f,0.f,0.f},{0.f,0.f,0.f,0.f},
                 {0.f,0.f,0.f,0.f},{0.f,0.f,0.f,0.f}};
    for (int k0 = 0; k0 < HDIM; k0 += 32) {
        s8v a = *(const s8v*)&h[(size_t)(m0 + col) * HDIM + k0 + quad * 8];
        #pragma unroll
        for (int t = 0; t < 4; ++t) {
            s8v b = *(const s8v*)&W2t[(size_t)(c0 + t * 16 + col) * HDIM + k0 + quad * 8];
            acc[t] = __builtin_amdgcn_mfma_f32_16x16x32_bf16(a, b, acc[t], 0, 0, 0);
        }
    }
    #pragma unroll
    for (int t = 0; t < 4; ++t) {
        int c = c0 + t * 16 + col;
        float bb = b2[c];
        #pragma unroll
        for (int r = 0; r < 4; ++r) {
            int m = m0 + quad * 4 + r;
            if (m < N) x[(size_t)m * DMODEL + c] = f2bf(acc[t][r] + bb);
        }
    }
}

// grid-stride dot over bf16 x, one atomic per block.
__global__ __launch_bounds__(256) void k_out_reduce(
    const bf16_t* __restrict__ x, const float* __restrict__ Wfc,
    float* __restrict__ acc, int NT) {
    __shared__ float sm[4];
    int tid = threadIdx.x;
    float v = 0.f;
    int np = NT / 2;
    const unsigned int* xp = (const unsigned int*)x;
    for (int i = blockIdx.x * blockDim.x + tid; i < np; i += gridDim.x * blockDim.x) {
        unsigned int u = xp[i];
        int c = (2 * i) & (DMODEL - 1);
        v = fmaf(bf_lo(u), Wfc[c], v);
        v = fmaf(bf_hi(u), Wfc[c + 1], v);
    }
    for (int off = 32; off > 0; off >>= 1) v += __shfl_xor(v, off, 64);
    if ((tid & 63) == 0) sm[tid >> 6] = v;
    __syncthreads();
    if (tid == 0) {
        float s = sm[0] + sm[1] + sm[2] + sm[3];
        atomicAdd(acc, s);
    }
}

__global__ void k_out_final(const float* __restrict__ acc, const float* __restrict__ bfc,
                            float* __restrict__ out, float invN) {
    out[0] = acc[0] * invN + bfc[0];
}

extern "C" void kernel_launch(void* const* d_in, const int* in_sizes, int n_in,
                              void* d_out, int out_size, void* d_ws, size_t ws_size,
                              hipStream_t stream) {
    const int*   an    = (const int*)d_in[0];
    const int*   gs    = (const int*)d_in[1];
    const int*   gd    = (const int*)d_in[2];
    const int*   ts    = (const int*)d_in[3];
    const int*   td    = (const int*)d_in[4];
    const float* r     = (const float*)d_in[5];
    const float* emb   = (const float*)d_in[6];
    const float* Wsrc  = (const float*)d_in[7];
    const float* bsrc  = (const float*)d_in[8];
    const float* Wdst  = (const float*)d_in[9];
    const float* bdst  = (const float*)d_in[10];
    const float* Wedge = (const float*)d_in[11];
    const float* bedge = (const float*)d_in[12];
    const float* attn  = (const float*)d_in[13];
    const float* W1    = (const float*)d_in[14];
    const float* b1    = (const float*)d_in[15];
    const float* W2    = (const float*)d_in[16];
    const float* b2    = (const float*)d_in[17];
    const float* Wfc   = (const float*)d_in[18];
    const float* bfc   = (const float*)d_in[19];

    const int N = in_sizes[0];
    const int E = in_sizes[1];
    const int T = in_sizes[3];

    char* w = (char*)d_ws;
    size_t off = 0;
    auto alloc = [&](size_t bytes) {
        void* p = w + off;
        off += (bytes + 255) & ~(size_t)255;
        return p;
    };
    bf16_t* xb     = (bf16_t*)alloc((size_t)(N + 64) * DMODEL * 2);
    float*  rn     = (float*) alloc((size_t)E * 3 * 4);
    float*  bl     = (float*) alloc(((size_t)E + 64) * 4);
    int*    cnt    = (int*)   alloc((size_t)E * 4);
    int*    rowp   = (int*)   alloc(((size_t)E + 1) * 4);
    int*    bsum   = (int*)   alloc(4096);
    int2*   packed = (int2*)  alloc((size_t)T * 8);
    int*    ecnt   = (int*)   alloc((size_t)N * 4);
    int*    erowp  = (int*)   alloc(((size_t)N + 1) * 4);
    int*    eord   = (int*)   alloc((size_t)E * 4);
    float*  xs     = (float*) alloc((size_t)N * DM * 4);
    float*  xd     = (float*) alloc((size_t)N * DM * 4);
    bf16_t* xij    = (bf16_t*)alloc((size_t)E * DM * 2);
    bf16_t* msg    = (bf16_t*)alloc((size_t)E * DM * 2);
    bf16_t* ft     = (bf16_t*)alloc((size_t)(N + 64) * DM * 2);
    bf16_t* hb     = (bf16_t*)alloc((size_t)(N + 64) * HDIM * 2);
    bf16_t* W1t    = (bf16_t*)alloc((size_t)3 * HDIM * DM * 2);
    bf16_t* W2t    = (bf16_t*)alloc((size_t)3 * DMODEL * HDIM * 2);
    bf16_t* Wedgt  = (bf16_t*)alloc((size_t)3 * DM * DMODEL * 2);
    bf16_t* Wst    = (bf16_t*)alloc((size_t)3 * DM * DMODEL * 2);
    bf16_t* Wdt    = (bf16_t*)alloc((size_t)3 * DM * DMODEL * 2);
    float*  accs   = (float*) alloc(64);
    (void)ws_size; (void)n_in; (void)out_size;

    const int nbScanE = (E + 255) / 256;
    const int nbScanN = (N + 255) / 256;

    // ---- setup (layer-invariant) ----
    k_embed<<<N, 256, 0, stream>>>(an, emb, xb);
    k_edge_geom<<<(E + 255) / 256, 256, 0, stream>>>(r, bl, rn, E);
    for (int l = 0; l < 3; ++l) {
        k_castT<<<dim3(DM / 32, HDIM / 32), 256, 0, stream>>>(
            W1 + (size_t)l * DM * HDIM, W1t + (size_t)l * HDIM * DM, DM, HDIM);
        k_castT<<<dim3(HDIM / 32, DMODEL / 32), 256, 0, stream>>>(
            W2 + (size_t)l * HDIM * DMODEL, W2t + (size_t)l * DMODEL * HDIM,
            HDIM, DMODEL);
        k_castT<<<dim3(DMODEL / 32, DM / 32), 256, 0, stream>>>(
            Wedge + (size_t)l * DMODEL * DM, Wedgt + (size_t)l * DM * DMODEL,
            DMODEL, DM);
        k_castT<<<dim3(DMODEL / 32, DM / 32), 256, 0, stream>>>(
            Wsrc + (size_t)l * DMODEL * DM, Wst + (size_t)l * DM * DMODEL,
            DMODEL, DM);
        k_castT<<<dim3(DMODEL / 32, DM / 32), 256, 0, stream>>>(
            Wdst + (size_t)l * DMODEL * DM, Wdt + (size_t)l * DM * DMODEL,
            DMODEL, DM);
    }
    // triplet CSR by t_dst
    hipMemsetAsync(cnt, 0, (size_t)E * 4, stream);
    k_hist<<<(T + 255) / 256, 256, 0, stream>>>(td, cnt, T);
    k_scan_part<<<nbScanE, 256, 0, stream>>>(cnt, bsum, E);
    k_scan_mid<<<1, 1024, 0, stream>>>(bsum, nbScanE);
    k_scan_final<<<nbScanE, 256, 0, stream>>>(cnt, bsum, rowp, E, T);
    hipMemsetAsync(cnt, 0, (size_t)E * 4, stream);
    k_scatter<<<(T + 255) / 256, 256, 0, stream>>>(ts, td, rowp, cnt, rn,
                                                   packed, T);
    // edge CSR by gd
    hipMemsetAsync(ecnt, 0, (size_t)N * 4, stream);
    k_hist<<<(E + 255) / 256, 256, 0, stream>>>(gd, ecnt, E);
    k_scan_part<<<nbScanN, 256, 0, stream>>>(ecnt, bsum, N);
    k_scan_mid<<<1, 1024, 0, stream>>>(bsum, nbScanN);
    k_scan_final<<<nbScanN, 256, 0, stream>>>(ecnt, bsum, erowp, N, E);
    hipMemsetAsync(ecnt, 0, (size_t)N * 4, stream);
    k_escatter<<<(E + 255) / 256, 256, 0, stream>>>(gd, erowp, ecnt, eord, E);

    // ---- layers ----
    for (int l = 0; l < 3; ++l) {
        k_node_proj<<<(N + 63) / 64, 256, 0, stream>>>(
            xb, Wst + (size_t)l * DM * DMODEL, bsrc + l * DM,
            Wdt + (size_t)l * DM * DMODEL, bdst + l * DM, xs, xd, N);
        k_xij<<<(E + 63) / 64, 256, 0, stream>>>(
            bl, Wedgt + (size_t)l * DM * DMODEL, bedge + l * DM,
            xs, xd, gs, gd, xij, E);
        k_edge_attn<<<(E * 16 + 255) / 256, 256, 0, stream>>>(
            xij, packed, rowp, attn + l * DM, msg, E);
        k_aggregate<<<(N * 16 + 255) / 256, 256, 0, stream>>>(
            msg, erowp, eord, ft, N);
        k_ffn1<<<dim3((N + 63) / 64, HDIM / 64), 256, 0, stream>>>(
            ft, W1t + (size_t)l * HDIM * DM, b1 + l * HDIM, hb, N);
        k_ffn2<<<dim3((N + 63) / 64, DMODEL / 64), 256, 0, stream>>>(
            hb, W2t + (size_t)l * DMODEL * HDIM, b2 + l * DMODEL, xb, N);
    }

    // ---- output head ----
    hipMemsetAsync(accs, 0, 4, stream);
    k_out_reduce<<<120, 256, 0, stream>>>(xb, Wfc, accs, N * DMODEL);
    k_out_final<<<1, 1, 0, stream>>>(accs, bfc, (float*)d_out, 1.0f / (float)N);
}